// Round 10
// baseline (135.839 us; speedup 1.0000x reference)
//
#include <hip/hip_runtime.h>
#include <hip/hip_bf16.h>

constexpr int CH = 128;    // channels
constexpr int NPOS = 4096; // h*w
constexpr int NB = 4;      // batch
constexpr int SPLITS = 16; // split-K factor for flash attention

typedef __bf16 bf16x8 __attribute__((ext_vector_type(8)));
typedef float f32x2 __attribute__((ext_vector_type(2)));
typedef float f32x16 __attribute__((ext_vector_type(16)));

// (1/sqrt(128)) * log2(e): fold softmax scale into Qb so MFMA emits exp2-domain
constexpr float CSC = 0.08838834764831845f * 1.4426950408889634f;

// Frag-native layout for Q/K (mfma_32x32x16 A/B operand order):
// [b][t32 = pos>>5][kf = c>>4][lane][j]; lane = (pos&31) + 32*((c>>3)&1),
// j = c&7. One (t32,kf) chunk = contiguous 1 KB; one t32 tile = 8 KB.

// Async global->LDS DMA, 16B per lane, LDS dst = wave-uniform base + lane*16.
__device__ __forceinline__ void async_copy16(const void* g, void* l) {
  auto gp = (const __attribute__((address_space(1))) unsigned int*)((uintptr_t)g);
  auto lp = (__attribute__((address_space(3))) unsigned int*)((uintptr_t)l);
  __builtin_amdgcn_global_load_lds(gp, lp, 16, 0, 0);
}

// ---------------------------------------------------------------------------
// Fuse kernel: Wqk = Wk @ Wq, bqk = Wk@bq + bk; bf16 copies of Wq, Wqk.
// ---------------------------------------------------------------------------
__global__ __launch_bounds__(128) void fuse_w_kernel(
    const float* __restrict__ Wq, const float* __restrict__ bq,
    const float* __restrict__ Wk, const float* __restrict__ bk,
    __bf16* __restrict__ Wqb, __bf16* __restrict__ Wqkb,
    float* __restrict__ bqk) {
  __shared__ float red[CH];
  const int o = blockIdx.x;
  const int i = threadIdx.x;
  float acc = 0.f;
#pragma unroll 8
  for (int m = 0; m < CH; m++) acc += Wk[o * CH + m] * Wq[m * CH + i];
  Wqkb[o * CH + i] = (__bf16)acc;
  Wqb[o * CH + i] = (__bf16)Wq[o * CH + i];
  red[i] = Wk[o * CH + i] * bq[i];
  __syncthreads();
  if (i == 0) {
    float s = 0.f;
    for (int m = 0; m < CH; m++) s += red[m];
    bqk[o] = s + bk[o];
  }
}

// ---------------------------------------------------------------------------
// Projection via mfma_32x32x16_bf16. Grid 1024 x 256: block = (b, u, z) with
// u in [0,128) (32-pos tile), z in {0,1}; wave w = output col group n=w.
// A-frag loads are redundant across the 4 waves (L1/L2-resident).
// XCD-affinity: batch b -> XCDs {2b, 2b+1}.
// ---------------------------------------------------------------------------
__global__ __launch_bounds__(256) void proj_kernel(
    const float* __restrict__ feature0, const __bf16* __restrict__ Wqb,
    const float* __restrict__ bq, const __bf16* __restrict__ Wqkb,
    const float* __restrict__ bqk, __bf16* __restrict__ Qf,
    __bf16* __restrict__ Kf) {
  const int bid = blockIdx.x;  // 1024 blocks
  const int b = (bid >> 1) & 3;
  const int rest = (bid >> 3) * 2 + (bid & 1);  // 0..255 per batch
  const int u = rest >> 1, z = rest & 1;        // u: 0..127 (pos tile)
  const int n = threadIdx.x >> 6;  // wave = output col group
  const int lane = threadIdx.x & 63;
  const int half = lane >> 5, l31 = lane & 31;
  const int pos = u * 32 + l31;

  bf16x8 A[8];
#pragma unroll
  for (int ks = 0; ks < 8; ks++) {
    float v[8];
#pragma unroll
    for (int j = 0; j < 8; j++)
      v[j] = feature0[(size_t)(b * CH + ks * 16 + half * 8 + j) * NPOS + pos];
#pragma unroll
    for (int j = 0; j < 8; j++) A[ks][j] = (__bf16)v[j];
  }

  const __bf16* W = z ? Wqkb : Wqb;
  const float* bias = z ? bqk : bq;
  __bf16* Out = z ? Kf : Qf;
  const float scale = z ? 1.0f : CSC;

  const int co = n * 32 + l31;
  const bf16x8* Bp = (const bf16x8*)(W + co * CH + half * 8);
  f32x16 c = {0.f, 0.f, 0.f, 0.f, 0.f, 0.f, 0.f, 0.f,
              0.f, 0.f, 0.f, 0.f, 0.f, 0.f, 0.f, 0.f};
#pragma unroll
  for (int ks = 0; ks < 8; ks++)
    c = __builtin_amdgcn_mfma_f32_32x32x16_bf16(A[ks], Bp[ks * 2], c, 0, 0, 0);
  const float bv = bias[co];
  const int kf = n * 2 + (l31 >> 4);
  const int lanebit = (l31 >> 3) & 1;
  const int j = l31 & 7;
#pragma unroll
  for (int r = 0; r < 16; r++) {
    int roff = (r & 3) + 8 * (r >> 2) + 4 * half;  // pos offset in tile
    Out[((((size_t)(b * (NPOS / 32) + u)) * 8 + kf) * 64 +
         (roff + 32 * lanebit)) * 8 + j] = (__bf16)((c[r] + bv) * scale);
  }
}

// ---------------------------------------------------------------------------
// Flash attention, split-K, no running max (scores exp2-domain bounded;
// verified R1-R8). WAVE-SPECIALIZED producer/consumer:
//   wave 4  = producer: global_load_lds DMA of 8 KB K-tiles into a 3-deep
//             circular buffer, throttled by "s_waitcnt vmcnt(8); s_barrier"
//             (tile t+1 complete at barrier t; one tile always in flight).
//             vmcnt is per-wave state — nothing else drains it.
//   waves 0-3 = consumers: ZERO vmem in the loop; raw symmetric barriers
//             (vmcnt(0) is free for them), precise lgkm ds_read->MFMA.
// Both sides execute exactly NT+2 = 10 barriers, verified pairwise:
//   B1 = prolog (tile0 ready / flds+qf staged); B2..B9 = end of tile t
//   (signals reads of buf t%3 done; tile t+1 ready); B10 = red handoff.
// mfma_32x32x16: wave owns 32 q rows; block = 128 q rows x 256 keys.
// ---------------------------------------------------------------------------
#define CONS_BARRIER() \
  asm volatile("s_waitcnt vmcnt(0) lgkmcnt(0)\n\ts_barrier" ::: "memory")
#define PROD_BARRIER(N) \
  asm volatile("s_waitcnt vmcnt(" #N ")\n\ts_barrier" ::: "memory")

__global__ __launch_bounds__(320, 4) void attn_kernel(
    const __bf16* __restrict__ Qf, const __bf16* __restrict__ Kf,
    const float* __restrict__ flow, float* __restrict__ part) {
  __shared__ __bf16 Klds[3][4096];  // 3 x 8 KB (32 keys x 128 c each)
  __shared__ float flds[2 * 256];   // split's flow values
  __shared__ float red[128 * 3];

  const int bid = blockIdx.x;  // 2048 blocks
  const int b = (bid >> 1) & 3;
  const int u = (bid >> 3) * 2 + (bid & 1);  // 0..511 per batch
  const int split = u >> 5;                  // 16 splits
  const int qg = u & 31;                     // 32 q-groups of 128 rows

  const int tid = threadIdx.x;
  const int wave = tid >> 6, lane = tid & 63;
  const int half = lane >> 5, l31 = lane & 31;
  constexpr int NT = 8;  // 8 tiles of 32 keys = 256 keys per split

  // K tile base for this (b, split): 8 contiguous 8 KB frag-native tiles
  const __bf16* Ktb = Kf + ((size_t)(b * (NPOS / 32) + split * 8)) * 4096;

  if (wave == 4) {
    // ---------------- producer ----------------
    auto issue = [&](int t) {
      const __bf16* g = Ktb + (size_t)t * 4096;
      __bf16* l = &Klds[t % 3][0];
#pragma unroll
      for (int i = 0; i < 8; i++)
        async_copy16(g + i * 512 + lane * 8, l + i * 512 + lane * 8);
    };
    issue(0);
    issue(1);
    PROD_BARRIER(8);  // B1: tile 0 complete (tile 1's 8 may be outstanding)
    for (int t = 0; t < NT; t++) {
      if (t + 2 < NT) {
        issue(t + 2);     // overwrites buf (t-1)%3; reads done at B_{t+1}
        PROD_BARRIER(8);  // B_{t+2}: tile t+1 complete
      } else {
        PROD_BARRIER(0);  // B_{t+2}: final tiles complete
      }
    }
    asm volatile("s_barrier" ::: "memory");  // B10
  } else {
    // ---------------- consumers (tid 0..255) ----------------
    {
      const float* fl0 = flow + (size_t)(b * 2 + 0) * NPOS + split * 256;
      const float* fl1 = flow + (size_t)(b * 2 + 1) * NPOS + split * 256;
      flds[tid] = fl0[tid];
      flds[256 + tid] = fl1[tid];
    }
    const int qt = qg * 4 + wave;  // wave's 32 q rows (CSC pre-folded)
    bf16x8 qf[8];
    {
      const bf16x8* Qp =
          (const bf16x8*)Qf + ((size_t)(b * (NPOS / 32) + qt) * 8) * 64 + lane;
#pragma unroll
      for (int kf = 0; kf < 8; kf++) qf[kf] = Qp[kf * 64];
    }
    float ls[16];
    f32x2 av[16];
#pragma unroll
    for (int r = 0; r < 16; r++) {
      ls[r] = 0.f;
      av[r] = f32x2{0.f, 0.f};
    }

    CONS_BARRIER();  // B1: tile 0 ready; our flds stores drained (lgkm)

    for (int t = 0; t < NT; t++) {
      const __bf16* kb = &Klds[t % 3][0];
      f32x16 c = {0.f, 0.f, 0.f, 0.f, 0.f, 0.f, 0.f, 0.f,
                  0.f, 0.f, 0.f, 0.f, 0.f, 0.f, 0.f, 0.f};
#pragma unroll
      for (int kf = 0; kf < 8; kf++) {
        bf16x8 bfrag = *(const bf16x8*)(kb + kf * 512 + lane * 8);
        c = __builtin_amdgcn_mfma_f32_32x32x16_bf16(qf[kf], bfrag, c, 0, 0, 0);
      }
      const f32x2 v01 = {flds[t * 32 + l31], flds[256 + t * 32 + l31]};
#pragma unroll
      for (int r = 0; r < 16; r++) {
        float p = __builtin_amdgcn_exp2f(c[r]);
        ls[r] += p;
        av[r] += f32x2{p, p} * v01;
      }
      CONS_BARRIER();  // B2..B9: our reads of buf t%3 done; tile t+1 ready
    }

    // reduce across the 32 key-lanes (butterfly within each 32-lane half)
#pragma unroll
    for (int r = 0; r < 16; r++) {
#pragma unroll
      for (int st = 1; st < 32; st <<= 1) {
        ls[r] += __shfl_xor(ls[r], st, 64);
        av[r][0] += __shfl_xor(av[r][0], st, 64);
        av[r][1] += __shfl_xor(av[r][1], st, 64);
      }
    }
    if (l31 == 0) {
#pragma unroll
      for (int r = 0; r < 16; r++) {
        int ql = wave * 32 + (r & 3) + 8 * (r >> 2) + 4 * half;
        red[ql * 3 + 0] = ls[r];
        red[ql * 3 + 1] = av[r][0];
        red[ql * 3 + 2] = av[r][1];
      }
    }
    CONS_BARRIER();  // B10: red visible
    for (int idx = tid; idx < 128 * 3; idx += 256) {
      int plane = idx / 128, ql = idx % 128;
      part[((size_t)(plane * SPLITS + split) * NB + b) * NPOS + qg * 128 +
           ql] = red[ql * 3 + plane];
    }
  }
}

// ---------------------------------------------------------------------------
// Combine: sum split partials per plane, normalize, write out[b][2][n].
// ---------------------------------------------------------------------------
__global__ __launch_bounds__(256) void combine_kernel(
    const float* __restrict__ part, float* __restrict__ out) {
  int t = blockIdx.x * 256 + threadIdx.x;  // 0 .. NB*NPOS-1
  int b = t >> 12, q = t & (NPOS - 1);
  float l = 0.f, x = 0.f, y = 0.f;
#pragma unroll
  for (int s = 0; s < SPLITS; s++) {
    l += part[((size_t)(0 * SPLITS + s) * NB + b) * NPOS + q];
    x += part[((size_t)(1 * SPLITS + s) * NB + b) * NPOS + q];
    y += part[((size_t)(2 * SPLITS + s) * NB + b) * NPOS + q];
  }
  float inv = 1.0f / l;
  out[(size_t)(b * 2 + 0) * NPOS + q] = x * inv;
  out[(size_t)(b * 2 + 1) * NPOS + q] = y * inv;
}

extern "C" void kernel_launch(void* const* d_in, const int* in_sizes, int n_in,
                              void* d_out, int out_size, void* d_ws,
                              size_t ws_size, hipStream_t stream) {
  const float* feature0 = (const float*)d_in[0];
  const float* flow = (const float*)d_in[1];
  const float* Wq = (const float*)d_in[2];
  const float* bq = (const float*)d_in[3];
  const float* Wk = (const float*)d_in[4];
  const float* bk = (const float*)d_in[5];
  float* out = (float*)d_out;

  char* ws = (char*)d_ws;
  __bf16* Qf = (__bf16*)ws;                                 // 4 MB
  __bf16* Kf = (__bf16*)(ws + (4 << 20));                   // 4 MB
  __bf16* Wqb = (__bf16*)(ws + (8 << 20));                  // 32 KB
  __bf16* Wqkb = (__bf16*)(ws + (8 << 20) + (32 << 10));    // 32 KB
  float* bqk = (float*)(ws + (8 << 20) + (64 << 10));       // 512 B
  float* part = (float*)(ws + (8 << 20) + (128 << 10));     // 3 MB

  fuse_w_kernel<<<dim3(CH), 128, 0, stream>>>(Wq, bq, Wk, bk, Wqb, Wqkb, bqk);
  proj_kernel<<<dim3(1024), 256, 0, stream>>>(feature0, Wqb, bq, Wqkb, bqk, Qf,
                                              Kf);
  attn_kernel<<<dim3(2048), 320, 0, stream>>>(Qf, Kf, flow, part);
  combine_kernel<<<dim3(NB * NPOS / 256), 256, 0, stream>>>(part, out);
}

// Round 11
// 124.147 us; speedup vs baseline: 1.0942x; 1.0942x over previous
//
#include <hip/hip_runtime.h>
#include <hip/hip_bf16.h>

constexpr int CH = 128;    // channels
constexpr int NPOS = 4096; // h*w
constexpr int NB = 4;      // batch
constexpr int SPLITS = 16; // split-K factor for flash attention

typedef __bf16 bf16x8 __attribute__((ext_vector_type(8)));
typedef float f32x2 __attribute__((ext_vector_type(2)));
typedef float f32x16 __attribute__((ext_vector_type(16)));

// (1/sqrt(128)) * log2(e): fold softmax scale into Qb so MFMA emits exp2-domain
constexpr float CSC = 0.08838834764831845f * 1.4426950408889634f;

// Frag-native layout for Q/K (mfma_32x32x16 A/B operand order):
// [b][t32 = pos>>5][kf = c>>4][lane][j]; lane = (pos&31) + 32*((c>>3)&1),
// j = c&7. One (t32,kf) chunk = contiguous 1 KB; one t32 tile = 8 KB.

// Async global->LDS DMA, 16B per lane, LDS dst = wave-uniform base + lane*16.
__device__ __forceinline__ void async_copy16(const void* g, void* l) {
  auto gp = (const __attribute__((address_space(1))) unsigned int*)((uintptr_t)g);
  auto lp = (__attribute__((address_space(3))) unsigned int*)((uintptr_t)l);
  __builtin_amdgcn_global_load_lds(gp, lp, 16, 0, 0);
}

// Barrier that requests only the oldest DMAs retired (best-measured variant,
// R7); compiler may still add its own waits, accepted as-is.
#define PIPE_BARRIER(N)                                              \
  asm volatile("s_waitcnt vmcnt(" #N ") lgkmcnt(0)\n\ts_barrier" ::: "memory")

// ---------------------------------------------------------------------------
// Fuse kernel: Wqk = Wk @ Wq, bqk = Wk@bq + bk; bf16 copies of Wq, Wqk.
// ---------------------------------------------------------------------------
__global__ __launch_bounds__(128) void fuse_w_kernel(
    const float* __restrict__ Wq, const float* __restrict__ bq,
    const float* __restrict__ Wk, const float* __restrict__ bk,
    __bf16* __restrict__ Wqb, __bf16* __restrict__ Wqkb,
    float* __restrict__ bqk) {
  __shared__ float red[CH];
  const int o = blockIdx.x;
  const int i = threadIdx.x;
  float acc = 0.f;
#pragma unroll 8
  for (int m = 0; m < CH; m++) acc += Wk[o * CH + m] * Wq[m * CH + i];
  Wqkb[o * CH + i] = (__bf16)acc;
  Wqb[o * CH + i] = (__bf16)Wq[o * CH + i];
  red[i] = Wk[o * CH + i] * bq[i];
  __syncthreads();
  if (i == 0) {
    float s = 0.f;
    for (int m = 0; m < CH; m++) s += red[m];
    bqk[o] = s + bk[o];
  }
}

// ---------------------------------------------------------------------------
// Projection via mfma_32x32x16_bf16 (R10's verified version). Grid 1024 x
// 256: block = (b, u, z), u in [0,128), z in {0,1}; wave w = col group n=w.
// XCD-affinity: batch b -> XCDs {2b, 2b+1}.
// ---------------------------------------------------------------------------
__global__ __launch_bounds__(256) void proj_kernel(
    const float* __restrict__ feature0, const __bf16* __restrict__ Wqb,
    const float* __restrict__ bq, const __bf16* __restrict__ Wqkb,
    const float* __restrict__ bqk, __bf16* __restrict__ Qf,
    __bf16* __restrict__ Kf) {
  const int bid = blockIdx.x;  // 1024 blocks
  const int b = (bid >> 1) & 3;
  const int rest = (bid >> 3) * 2 + (bid & 1);  // 0..255 per batch
  const int u = rest >> 1, z = rest & 1;        // u: 0..127 (pos tile)
  const int n = threadIdx.x >> 6;  // wave = output col group
  const int lane = threadIdx.x & 63;
  const int half = lane >> 5, l31 = lane & 31;
  const int pos = u * 32 + l31;

  bf16x8 A[8];
#pragma unroll
  for (int ks = 0; ks < 8; ks++) {
    float v[8];
#pragma unroll
    for (int j = 0; j < 8; j++)
      v[j] = feature0[(size_t)(b * CH + ks * 16 + half * 8 + j) * NPOS + pos];
#pragma unroll
    for (int j = 0; j < 8; j++) A[ks][j] = (__bf16)v[j];
  }

  const __bf16* W = z ? Wqkb : Wqb;
  const float* bias = z ? bqk : bq;
  __bf16* Out = z ? Kf : Qf;
  const float scale = z ? 1.0f : CSC;

  const int co = n * 32 + l31;
  const bf16x8* Bp = (const bf16x8*)(W + co * CH + half * 8);
  f32x16 c = {0.f, 0.f, 0.f, 0.f, 0.f, 0.f, 0.f, 0.f,
              0.f, 0.f, 0.f, 0.f, 0.f, 0.f, 0.f, 0.f};
#pragma unroll
  for (int ks = 0; ks < 8; ks++)
    c = __builtin_amdgcn_mfma_f32_32x32x16_bf16(A[ks], Bp[ks * 2], c, 0, 0, 0);
  const float bv = bias[co];
  const int kf = n * 2 + (l31 >> 4);
  const int lanebit = (l31 >> 3) & 1;
  const int j = l31 & 7;
#pragma unroll
  for (int r = 0; r < 16; r++) {
    int roff = (r & 3) + 8 * (r >> 2) + 4 * half;  // pos offset in tile
    Out[((((size_t)(b * (NPOS / 32) + u)) * 8 + kf) * 64 +
         (roff + 32 * lanebit)) * 8 + j] = (__bf16)((c[r] + bv) * scale);
  }
}

// ---------------------------------------------------------------------------
// Flash attention: EXACT R7 structure (best measured), with SPLITS 8->16:
// per-block serial tile rounds 16->8, grid 1024->2048. mfma_32x32x16, wave =
// 32 q rows, block = 128 q rows x 256 keys. 8 KB K-tiles DMA'd into a 3-deep
// circular buffer; PIPE_BARRIER(2) per tile; exp2 via builtin; av as f32x2.
// ---------------------------------------------------------------------------
__global__ __launch_bounds__(256, 4) void attn_kernel(
    const __bf16* __restrict__ Qf, const __bf16* __restrict__ Kf,
    const float* __restrict__ flow, float* __restrict__ part) {
  __shared__ __bf16 Klds[3][8 * 512];  // 3 x 8 KB circular buffer
  __shared__ float flds[2 * 256];      // split's flow values
  __shared__ float red[128 * 3];

  const int bid = blockIdx.x;  // 2048 blocks
  const int b = (bid >> 1) & 3;
  const int u = (bid >> 3) * 2 + (bid & 1);  // 0..511 per batch
  const int split = u >> 5;                  // 16 splits
  const int qg = u & 31;                     // 32 q-groups of 128 rows

  const int tid = threadIdx.x;
  const int wave = tid >> 6, lane = tid & 63;
  const int half = lane >> 5, l31 = lane & 31;
  const int kbase = split * (NPOS / SPLITS);  // 256 keys per split
  constexpr int NT = NPOS / SPLITS / 32;      // 8 tiles of 32 keys

  // stage flow for this split into LDS (one-time; fenced by first barrier)
  {
    const float* fl0 = flow + (size_t)(b * 2 + 0) * NPOS + kbase;
    const float* fl1 = flow + (size_t)(b * 2 + 1) * NPOS + kbase;
    if (tid < 256) {
      flds[tid] = fl0[tid];
      flds[256 + tid] = fl1[tid];
    }
  }

  // Q fragments: wave's 32 q rows = tile qt (CSC pre-folded)
  const int qt = qg * 4 + wave;  // 0..127
  bf16x8 qf[8];
  {
    const bf16x8* Qp =
        (const bf16x8*)Qf + ((size_t)(b * (NPOS / 32) + qt) * 8) * 64 + lane;
#pragma unroll
    for (int kf = 0; kf < 8; kf++) qf[kf] = Qp[kf * 64];
  }

  // K tile base for this (b, split): 8 contiguous 8 KB frag-native tiles
  const __bf16* Ktb = Kf + ((size_t)(b * (NPOS / 32) + (kbase >> 5))) * 4096;

  // wave w stages chunks 2w, 2w+1 of each tile (2 DMA insts per wave/tile)
  auto issue = [&](int t, int buf) {
    const __bf16* g = Ktb + (size_t)t * 4096;
#pragma unroll
    for (int cc = 0; cc < 2; cc++) {
      int chunk = wave * 2 + cc;
      async_copy16(g + chunk * 512 + lane * 8,
                   &Klds[buf][chunk * 512 + lane * 8]);
    }
  };
  issue(0, 0);
  issue(1, 1);

  float ls[16];
  f32x2 av[16];
#pragma unroll
  for (int r = 0; r < 16; r++) {
    ls[r] = 0.f;
    av[r] = f32x2{0.f, 0.f};
  }

  int bcur = 0, bnext = 2;  // buffer of tile t; buffer for tile t+2
  for (int t = 0; t < NT; t++) {
    PIPE_BARRIER(2);
    if (t + 2 < NT) issue(t + 2, bnext);

    const __bf16* kb = &Klds[bcur][0];
    f32x16 c = {0.f, 0.f, 0.f, 0.f, 0.f, 0.f, 0.f, 0.f,
                0.f, 0.f, 0.f, 0.f, 0.f, 0.f, 0.f, 0.f};
#pragma unroll
    for (int kf = 0; kf < 8; kf++) {
      bf16x8 bfrag = *(const bf16x8*)(kb + kf * 512 + lane * 8);
      c = __builtin_amdgcn_mfma_f32_32x32x16_bf16(qf[kf], bfrag, c, 0, 0, 0);
    }
    const f32x2 v01 = {flds[t * 32 + l31], flds[256 + t * 32 + l31]};
#pragma unroll
    for (int r = 0; r < 16; r++) {
      float p = __builtin_amdgcn_exp2f(c[r]);
      ls[r] += p;
      av[r] += f32x2{p, p} * v01;  // v_pk_fma_f32
    }
    bcur = (bcur == 2) ? 0 : bcur + 1;
    bnext = (bnext == 2) ? 0 : bnext + 1;
  }

  // reduce across the 32 key-lanes (butterfly stays within each 32-lane half)
#pragma unroll
  for (int r = 0; r < 16; r++) {
#pragma unroll
    for (int st = 1; st < 32; st <<= 1) {
      ls[r] += __shfl_xor(ls[r], st, 64);
      av[r][0] += __shfl_xor(av[r][0], st, 64);
      av[r][1] += __shfl_xor(av[r][1], st, 64);
    }
  }
  if (l31 == 0) {
#pragma unroll
    for (int r = 0; r < 16; r++) {
      int ql = wave * 32 + (r & 3) + 8 * (r >> 2) + 4 * half;
      red[ql * 3 + 0] = ls[r];
      red[ql * 3 + 1] = av[r][0];
      red[ql * 3 + 2] = av[r][1];
    }
  }
  __syncthreads();
  for (int idx = tid; idx < 128 * 3; idx += 256) {
    int plane = idx / 128, ql = idx % 128;
    part[((size_t)(plane * SPLITS + split) * NB + b) * NPOS + qg * 128 + ql] =
        red[ql * 3 + plane];
  }
}

// ---------------------------------------------------------------------------
// Combine: sum split partials per plane, normalize, write out[b][2][n].
// ---------------------------------------------------------------------------
__global__ __launch_bounds__(256) void combine_kernel(
    const float* __restrict__ part, float* __restrict__ out) {
  int t = blockIdx.x * 256 + threadIdx.x;  // 0 .. NB*NPOS-1
  int b = t >> 12, q = t & (NPOS - 1);
  float l = 0.f, x = 0.f, y = 0.f;
#pragma unroll
  for (int s = 0; s < SPLITS; s++) {
    l += part[((size_t)(0 * SPLITS + s) * NB + b) * NPOS + q];
    x += part[((size_t)(1 * SPLITS + s) * NB + b) * NPOS + q];
    y += part[((size_t)(2 * SPLITS + s) * NB + b) * NPOS + q];
  }
  float inv = 1.0f / l;
  out[(size_t)(b * 2 + 0) * NPOS + q] = x * inv;
  out[(size_t)(b * 2 + 1) * NPOS + q] = y * inv;
}

extern "C" void kernel_launch(void* const* d_in, const int* in_sizes, int n_in,
                              void* d_out, int out_size, void* d_ws,
                              size_t ws_size, hipStream_t stream) {
  const float* feature0 = (const float*)d_in[0];
  const float* flow = (const float*)d_in[1];
  const float* Wq = (const float*)d_in[2];
  const float* bq = (const float*)d_in[3];
  const float* Wk = (const float*)d_in[4];
  const float* bk = (const float*)d_in[5];
  float* out = (float*)d_out;

  char* ws = (char*)d_ws;
  __bf16* Qf = (__bf16*)ws;                                 // 4 MB
  __bf16* Kf = (__bf16*)(ws + (4 << 20));                   // 4 MB
  __bf16* Wqb = (__bf16*)(ws + (8 << 20));                  // 32 KB
  __bf16* Wqkb = (__bf16*)(ws + (8 << 20) + (32 << 10));    // 32 KB
  float* bqk = (float*)(ws + (8 << 20) + (64 << 10));       // 512 B
  float* part = (float*)(ws + (8 << 20) + (128 << 10));     // 3 MB

  fuse_w_kernel<<<dim3(CH), 128, 0, stream>>>(Wq, bq, Wk, bk, Wqb, Wqkb, bqk);
  proj_kernel<<<dim3(1024), 256, 0, stream>>>(feature0, Wqb, bq, Wqkb, bqk, Qf,
                                              Kf);
  attn_kernel<<<dim3(2048), 256, 0, stream>>>(Qf, Kf, flow, part);
  combine_kernel<<<dim3(NB * NPOS / 256), 256, 0, stream>>>(part, out);
}

// Round 12
// 113.475 us; speedup vs baseline: 1.1971x; 1.0941x over previous
//
#include <hip/hip_runtime.h>
#include <hip/hip_bf16.h>

constexpr int CH = 128;    // channels
constexpr int NPOS = 4096; // h*w
constexpr int NB = 4;      // batch
constexpr int SPLITS = 8;  // split-K factor for flash attention

typedef __bf16 bf16x8 __attribute__((ext_vector_type(8)));
typedef float f32x2 __attribute__((ext_vector_type(2)));
typedef float f32x16 __attribute__((ext_vector_type(16)));

// (1/sqrt(128)) * log2(e): fold softmax scale into Qb so MFMA emits exp2-domain
constexpr float CSC = 0.08838834764831845f * 1.4426950408889634f;

// Frag-native layout for Q/K (mfma_32x32x16 A/B operand order):
// [b][t32 = pos>>5][kf = c>>4][lane][j]; lane = (pos&31) + 32*((c>>3)&1),
// j = c&7. One (t32,kf) chunk = contiguous 1 KB; one t32 tile = 8 KB.

// Async global->LDS DMA, 16B per lane, LDS dst = wave-uniform base + lane*16.
__device__ __forceinline__ void async_copy16(const void* g, void* l) {
  auto gp = (const __attribute__((address_space(1))) unsigned int*)((uintptr_t)g);
  auto lp = (__attribute__((address_space(3))) unsigned int*)((uintptr_t)l);
  __builtin_amdgcn_global_load_lds(gp, lp, 16, 0, 0);
}

// Barrier requesting only the oldest DMA retired (R7's best-measured form).
#define PIPE_BARRIER(N)                                              \
  asm volatile("s_waitcnt vmcnt(" #N ") lgkmcnt(0)\n\ts_barrier" ::: "memory")

// ---------------------------------------------------------------------------
// Fuse kernel: Wqk = Wk @ Wq, bqk = Wk@bq + bk; bf16 copies of Wq, Wqk.
// ---------------------------------------------------------------------------
__global__ __launch_bounds__(128) void fuse_w_kernel(
    const float* __restrict__ Wq, const float* __restrict__ bq,
    const float* __restrict__ Wk, const float* __restrict__ bk,
    __bf16* __restrict__ Wqb, __bf16* __restrict__ Wqkb,
    float* __restrict__ bqk) {
  __shared__ float red[CH];
  const int o = blockIdx.x;
  const int i = threadIdx.x;
  float acc = 0.f;
#pragma unroll 8
  for (int m = 0; m < CH; m++) acc += Wk[o * CH + m] * Wq[m * CH + i];
  Wqkb[o * CH + i] = (__bf16)acc;
  Wqb[o * CH + i] = (__bf16)Wq[o * CH + i];
  red[i] = Wk[o * CH + i] * bq[i];
  __syncthreads();
  if (i == 0) {
    float s = 0.f;
    for (int m = 0; m < CH; m++) s += red[m];
    bqk[o] = s + bk[o];
  }
}

// ---------------------------------------------------------------------------
// Projection via mfma_32x32x16_bf16 (R10/R11's verified version). Grid 1024
// x 256: block = (b, u, z), u in [0,128), z in {0,1}; wave w = col group n.
// XCD-affinity: batch b -> XCDs {2b, 2b+1}.
// ---------------------------------------------------------------------------
__global__ __launch_bounds__(256) void proj_kernel(
    const float* __restrict__ feature0, const __bf16* __restrict__ Wqb,
    const float* __restrict__ bq, const __bf16* __restrict__ Wqkb,
    const float* __restrict__ bqk, __bf16* __restrict__ Qf,
    __bf16* __restrict__ Kf) {
  const int bid = blockIdx.x;  // 1024 blocks
  const int b = (bid >> 1) & 3;
  const int rest = (bid >> 3) * 2 + (bid & 1);  // 0..255 per batch
  const int u = rest >> 1, z = rest & 1;        // u: 0..127 (pos tile)
  const int n = threadIdx.x >> 6;  // wave = output col group
  const int lane = threadIdx.x & 63;
  const int half = lane >> 5, l31 = lane & 31;
  const int pos = u * 32 + l31;

  bf16x8 A[8];
#pragma unroll
  for (int ks = 0; ks < 8; ks++) {
    float v[8];
#pragma unroll
    for (int j = 0; j < 8; j++)
      v[j] = feature0[(size_t)(b * CH + ks * 16 + half * 8 + j) * NPOS + pos];
#pragma unroll
    for (int j = 0; j < 8; j++) A[ks][j] = (__bf16)v[j];
  }

  const __bf16* W = z ? Wqkb : Wqb;
  const float* bias = z ? bqk : bq;
  __bf16* Out = z ? Kf : Qf;
  const float scale = z ? 1.0f : CSC;

  const int co = n * 32 + l31;
  const bf16x8* Bp = (const bf16x8*)(W + co * CH + half * 8);
  f32x16 c = {0.f, 0.f, 0.f, 0.f, 0.f, 0.f, 0.f, 0.f,
              0.f, 0.f, 0.f, 0.f, 0.f, 0.f, 0.f, 0.f};
#pragma unroll
  for (int ks = 0; ks < 8; ks++)
    c = __builtin_amdgcn_mfma_f32_32x32x16_bf16(A[ks], Bp[ks * 2], c, 0, 0, 0);
  const float bv = bias[co];
  const int kf = n * 2 + (l31 >> 4);
  const int lanebit = (l31 >> 3) & 1;
  const int j = l31 & 7;
#pragma unroll
  for (int r = 0; r < 16; r++) {
    int roff = (r & 3) + 8 * (r >> 2) + 4 * half;  // pos offset in tile
    Out[((((size_t)(b * (NPOS / 32) + u)) * 8 + kf) * 64 +
         (roff + 32 * lanebit)) * 8 + j] = (__bf16)((c[r] + bv) * scale);
  }
}

// ---------------------------------------------------------------------------
// Flash attention: R7's structure with 512-THREAD BLOCKS (8 waves share each
// K tile). SPLITS=8; block = 256 q rows x 512 keys; wave = 32 q rows.
// Per-CU: DMA traffic and barrier rounds HALVE vs R7 (each round carries 2x
// compute). One DMA inst per wave per 8 KB tile; 3-deep circular buffer;
// PIPE_BARRIER(1) = tile t retired, tile t+1 still in flight.
// ---------------------------------------------------------------------------
__global__ __launch_bounds__(512, 2) void attn_kernel(
    const __bf16* __restrict__ Qf, const __bf16* __restrict__ Kf,
    const float* __restrict__ flow, float* __restrict__ part) {
  __shared__ __bf16 Klds[3][8 * 512];  // 3 x 8 KB circular buffer
  __shared__ float flds[2 * 512];      // split's flow values
  __shared__ float red[256 * 3];

  const int bid = blockIdx.x;  // 512 blocks
  const int b = (bid >> 1) & 3;
  const int u = (bid >> 3) * 2 + (bid & 1);  // 0..127 per batch
  const int split = u >> 4;                  // 8 splits
  const int qg = u & 15;                     // 16 q-groups of 256 rows

  const int tid = threadIdx.x;
  const int wave = tid >> 6, lane = tid & 63;
  const int half = lane >> 5, l31 = lane & 31;
  const int kbase = split * (NPOS / SPLITS);  // 512 keys per split
  constexpr int NT = NPOS / SPLITS / 32;      // 16 tiles of 32 keys

  // stage flow for this split into LDS (one-time; fenced by first barrier)
  {
    const float* fl0 = flow + (size_t)(b * 2 + 0) * NPOS + kbase;
    const float* fl1 = flow + (size_t)(b * 2 + 1) * NPOS + kbase;
    flds[tid] = fl0[tid];
    flds[512 + tid] = fl1[tid];
  }

  // Q fragments: wave's 32 q rows = tile qt (CSC pre-folded)
  const int qt = qg * 8 + wave;  // 0..127
  bf16x8 qf[8];
  {
    const bf16x8* Qp =
        (const bf16x8*)Qf + ((size_t)(b * (NPOS / 32) + qt) * 8) * 64 + lane;
#pragma unroll
    for (int kf = 0; kf < 8; kf++) qf[kf] = Qp[kf * 64];
  }

  // K tile base for this (b, split): 16 contiguous 8 KB frag-native tiles
  const __bf16* Ktb = Kf + ((size_t)(b * (NPOS / 32) + (kbase >> 5))) * 4096;

  // wave w stages chunk w (1 KB) of each tile: ONE DMA inst per wave/tile
  auto issue = [&](int t, int buf) {
    const __bf16* g = Ktb + (size_t)t * 4096;
    async_copy16(g + wave * 512 + lane * 8,
                 &Klds[buf][wave * 512 + lane * 8]);
  };
  issue(0, 0);
  issue(1, 1);

  float ls[16];
  f32x2 av[16];
#pragma unroll
  for (int r = 0; r < 16; r++) {
    ls[r] = 0.f;
    av[r] = f32x2{0.f, 0.f};
  }

  int bcur = 0, bnext = 2;  // buffer of tile t; buffer for tile t+2
  for (int t = 0; t < NT; t++) {
    PIPE_BARRIER(1);  // tile t's DMA (oldest) retired; t+1 stays in flight
    if (t + 2 < NT) issue(t + 2, bnext);

    const __bf16* kb = &Klds[bcur][0];
    f32x16 c = {0.f, 0.f, 0.f, 0.f, 0.f, 0.f, 0.f, 0.f,
                0.f, 0.f, 0.f, 0.f, 0.f, 0.f, 0.f, 0.f};
#pragma unroll
    for (int kf = 0; kf < 8; kf++) {
      bf16x8 bfrag = *(const bf16x8*)(kb + kf * 512 + lane * 8);
      c = __builtin_amdgcn_mfma_f32_32x32x16_bf16(qf[kf], bfrag, c, 0, 0, 0);
    }
    const f32x2 v01 = {flds[t * 32 + l31], flds[512 + t * 32 + l31]};
#pragma unroll
    for (int r = 0; r < 16; r++) {
      float p = __builtin_amdgcn_exp2f(c[r]);
      ls[r] += p;
      av[r] += f32x2{p, p} * v01;  // v_pk_fma_f32
    }
    bcur = (bcur == 2) ? 0 : bcur + 1;
    bnext = (bnext == 2) ? 0 : bnext + 1;
  }

  // reduce across the 32 key-lanes (butterfly stays within each 32-lane half)
#pragma unroll
  for (int r = 0; r < 16; r++) {
#pragma unroll
    for (int st = 1; st < 32; st <<= 1) {
      ls[r] += __shfl_xor(ls[r], st, 64);
      av[r][0] += __shfl_xor(av[r][0], st, 64);
      av[r][1] += __shfl_xor(av[r][1], st, 64);
    }
  }
  if (l31 == 0) {
#pragma unroll
    for (int r = 0; r < 16; r++) {
      int ql = wave * 32 + (r & 3) + 8 * (r >> 2) + 4 * half;
      red[ql * 3 + 0] = ls[r];
      red[ql * 3 + 1] = av[r][0];
      red[ql * 3 + 2] = av[r][1];
    }
  }
  __syncthreads();
  for (int idx = tid; idx < 256 * 3; idx += 512) {
    int plane = idx >> 8, ql = idx & 255;
    part[((size_t)(plane * SPLITS + split) * NB + b) * NPOS + qg * 256 + ql] =
        red[ql * 3 + plane];
  }
}

// ---------------------------------------------------------------------------
// Combine: sum split partials per plane, normalize, write out[b][2][n].
// ---------------------------------------------------------------------------
__global__ __launch_bounds__(256) void combine_kernel(
    const float* __restrict__ part, float* __restrict__ out) {
  int t = blockIdx.x * 256 + threadIdx.x;  // 0 .. NB*NPOS-1
  int b = t >> 12, q = t & (NPOS - 1);
  float l = 0.f, x = 0.f, y = 0.f;
#pragma unroll
  for (int s = 0; s < SPLITS; s++) {
    l += part[((size_t)(0 * SPLITS + s) * NB + b) * NPOS + q];
    x += part[((size_t)(1 * SPLITS + s) * NB + b) * NPOS + q];
    y += part[((size_t)(2 * SPLITS + s) * NB + b) * NPOS + q];
  }
  float inv = 1.0f / l;
  out[(size_t)(b * 2 + 0) * NPOS + q] = x * inv;
  out[(size_t)(b * 2 + 1) * NPOS + q] = y * inv;
}

extern "C" void kernel_launch(void* const* d_in, const int* in_sizes, int n_in,
                              void* d_out, int out_size, void* d_ws,
                              size_t ws_size, hipStream_t stream) {
  const float* feature0 = (const float*)d_in[0];
  const float* flow = (const float*)d_in[1];
  const float* Wq = (const float*)d_in[2];
  const float* bq = (const float*)d_in[3];
  const float* Wk = (const float*)d_in[4];
  const float* bk = (const float*)d_in[5];
  float* out = (float*)d_out;

  char* ws = (char*)d_ws;
  __bf16* Qf = (__bf16*)ws;                                 // 4 MB
  __bf16* Kf = (__bf16*)(ws + (4 << 20));                   // 4 MB
  __bf16* Wqb = (__bf16*)(ws + (8 << 20));                  // 32 KB
  __bf16* Wqkb = (__bf16*)(ws + (8 << 20) + (32 << 10));    // 32 KB
  float* bqk = (float*)(ws + (8 << 20) + (64 << 10));       // 512 B
  float* part = (float*)(ws + (8 << 20) + (128 << 10));     // 1.5 MB

  fuse_w_kernel<<<dim3(CH), 128, 0, stream>>>(Wq, bq, Wk, bk, Wqb, Wqkb, bqk);
  proj_kernel<<<dim3(1024), 256, 0, stream>>>(feature0, Wqb, bq, Wqkb, bqk, Qf,
                                              Kf);
  attn_kernel<<<dim3(512), 512, 0, stream>>>(Qf, Kf, flow, part);
  combine_kernel<<<dim3(NB * NPOS / 256), 256, 0, stream>>>(part, out);
}